// Round 6
// baseline (408.224 us; speedup 1.0000x reference)
//
#include <hip/hip_runtime.h>
#include <cfloat>
#include <cmath>

#define N_NODES 10000
#define E_EDGES 80000
#define R_REL   12
#define H_DIM   128
#define IN_DIM  64
#define OUT_DIM 64

// ---------------------------------------------------------------------------
// CSR build (by destination node, per relation). EL = src ids, DL = dst ids.
// ---------------------------------------------------------------------------
__global__ void hist_kernel(const int* __restrict__ EI, int* __restrict__ cnt) {
  int e = blockIdx.x * blockDim.x + threadIdx.x;
  int r = blockIdx.y;
  if (e >= E_EDGES) return;
  int dst = EI[(2 * r + 1) * E_EDGES + e];
  atomicAdd(&cnt[r * N_NODES + dst], 1);
}

// Block-parallel exclusive scan: one 1024-thread block per relation.
#define SCAN_E 10
__global__ __launch_bounds__(1024) void scan_kernel(int* __restrict__ cnt,
                                                    int* __restrict__ off) {
  const int r = blockIdx.x;
  const int t = threadIdx.x;
  const int lane = t & 63, wv = t >> 6;  // 16 waves
  __shared__ int wsum[16];

  const int base = t * SCAN_E;
  int v[SCAN_E];
  int s = 0;
  #pragma unroll
  for (int k = 0; k < SCAN_E; ++k) {
    int i = base + k;
    v[k] = (i < N_NODES) ? cnt[r * N_NODES + i] : 0;
    s += v[k];
  }
  int incl = s;
  #pragma unroll
  for (int o = 1; o < 64; o <<= 1) {
    int u = __shfl_up(incl, o);
    if (lane >= o) incl += u;
  }
  if (lane == 63) wsum[wv] = incl;
  __syncthreads();
  if (wv == 0) {
    int ws = (lane < 16) ? wsum[lane] : 0;
    int wi = ws;
    #pragma unroll
    for (int o = 1; o < 16; o <<= 1) {
      int u = __shfl_up(wi, o);
      if (lane >= o) wi += u;
    }
    if (lane < 16) wsum[lane] = wi - ws;  // exclusive wave prefix
  }
  __syncthreads();
  int run = wsum[wv] + incl - s;
  #pragma unroll
  for (int k = 0; k < SCAN_E; ++k) {
    int i = base + k;
    if (i < N_NODES) {
      off[r * (N_NODES + 1) + i] = run;
      cnt[r * N_NODES + i] = run;  // becomes fill cursor
      run += v[k];
    }
  }
  if (t == 1023) off[r * (N_NODES + 1) + N_NODES] = run;
}

__global__ void fill_kernel(const int* __restrict__ EI, int* __restrict__ cur,
                            int* __restrict__ EL, int* __restrict__ DL) {
  int e = blockIdx.x * blockDim.x + threadIdx.x;
  int r = blockIdx.y;
  if (e >= E_EDGES) return;
  int dst = EI[(2 * r + 1) * E_EDGES + e];
  int src = EI[(2 * r + 0) * E_EDGES + e];
  int pos = atomicAdd(&cur[r * N_NODES + dst], 1);
  EL[r * E_EDGES + pos] = src;
  DL[r * E_EDGES + pos] = dst;
}

// ---------------------------------------------------------------------------
// vsrc[r] = Wsrc[r] @ asrc[r], vdst[r] = Wdst[r] @ adst[r]   (tiny)
// ---------------------------------------------------------------------------
template <int K>
__global__ void vcomp_kernel(const float* __restrict__ Wsrc, const float* __restrict__ asrc,
                             const float* __restrict__ Wdst, const float* __restrict__ adst,
                             float* __restrict__ VS, float* __restrict__ VD) {
  const int r = blockIdx.x;
  const int k = threadIdx.x;  // K threads
  const float* w1 = Wsrc + ((size_t)r * K + k) * H_DIM;
  const float* w2 = Wdst + ((size_t)r * K + k) * H_DIM;
  const float* a1 = asrc + r * H_DIM;
  const float* a2 = adst + r * H_DIM;
  float s1 = 0.f, s2 = 0.f;
  for (int h = 0; h < H_DIM; ++h) {
    s1 = fmaf(w1[h], a1[h], s1);
    s2 = fmaf(w2[h], a2[h], s2);
  }
  VS[r * H_DIM + k] = s1;
  VD[r * H_DIM + k] = s2;
}

// ---------------------------------------------------------------------------
// XS[r] = X[src_type(r)] @ Wsrc[r] : [N,K]@[K,128], fp32 tiled GEMM
// ---------------------------------------------------------------------------
template <int K, bool PRUNED>
__global__ __launch_bounds__(256) void gemm_xs_kernel(
    const float* __restrict__ p0, const float* __restrict__ p1,
    const float* __restrict__ p2, const float* __restrict__ p3,
    const float* __restrict__ W,   // [R][K][H]
    float* __restrict__ XS) {      // [R][N][H]
  const int r = PRUNED ? 3 * (blockIdx.y + 1) : blockIdx.y;
  const int s = PRUNED ? (blockIdx.y + 1) : (r / 3);  // SRC_T[r]
  const float* __restrict__ X = (s == 0) ? p0 : (s == 1) ? p1 : (s == 2) ? p2 : p3;
  const int row0 = blockIdx.x * 128;
  const int tid = threadIdx.x;
  const int tx = tid & 15, ty = tid >> 4;
  __shared__ float Xst[32][132];  // [k][row], padded
  __shared__ float Ws[32][132];   // [k][col], padded

  float acc[8][8];
  #pragma unroll
  for (int i = 0; i < 8; ++i)
    #pragma unroll
    for (int j = 0; j < 8; ++j) acc[i][j] = 0.f;

  const float* Wr = W + (size_t)r * K * H_DIM;

  #pragma unroll 1
  for (int k0 = 0; k0 < K; k0 += 32) {
    #pragma unroll
    for (int p = 0; p < 4; ++p) {
      int idx = tid + p * 256;   // 0..1023 float4 slots
      int row = idx >> 3;        // 8 float4 per row
      int kq = idx & 7;
      float4 v = {0.f, 0.f, 0.f, 0.f};
      int grow = row0 + row;
      if (grow < N_NODES)
        v = *(const float4*)(X + (size_t)grow * K + k0 + kq * 4);
      Xst[kq * 4 + 0][row] = v.x;
      Xst[kq * 4 + 1][row] = v.y;
      Xst[kq * 4 + 2][row] = v.z;
      Xst[kq * 4 + 3][row] = v.w;
    }
    #pragma unroll
    for (int p = 0; p < 4; ++p) {
      int idx = tid + p * 256;
      int kk = idx >> 5;  // 32 float4 per row
      int cq = idx & 31;
      float4 v = *(const float4*)(Wr + (size_t)(k0 + kk) * H_DIM + cq * 4);
      *(float4*)&Ws[kk][cq * 4] = v;
    }
    __syncthreads();
    #pragma unroll
    for (int kk = 0; kk < 32; ++kk) {
      float a[8], b[8];
      *(float4*)&a[0] = *(float4*)&Xst[kk][ty * 8];
      *(float4*)&a[4] = *(float4*)&Xst[kk][ty * 8 + 4];
      *(float4*)&b[0] = *(float4*)&Ws[kk][tx * 8];
      *(float4*)&b[4] = *(float4*)&Ws[kk][tx * 8 + 4];
      #pragma unroll
      for (int i = 0; i < 8; ++i)
        #pragma unroll
        for (int j = 0; j < 8; ++j) acc[i][j] = fmaf(a[i], b[j], acc[i][j]);
    }
    __syncthreads();
  }
  float* outp = XS + (size_t)r * N_NODES * H_DIM;
  #pragma unroll
  for (int i = 0; i < 8; ++i) {
    int row = row0 + ty * 8 + i;
    if (row < N_NODES) {
      *(float4*)(outp + (size_t)row * H_DIM + tx * 8) = *(float4*)&acc[i][0];
      *(float4*)(outp + (size_t)row * H_DIM + tx * 8 + 4) = *(float4*)&acc[i][4];
    }
  }
}

// ---------------------------------------------------------------------------
// AS[r][n] = X[src_t][n] . VS[r] ;  AD[r][n] = X[dst_t][n] . VD[r]
// ---------------------------------------------------------------------------
template <int K, bool PRUNED>
__global__ __launch_bounds__(256) void attn_coef_kernel(
    const float* __restrict__ p0, const float* __restrict__ p1,
    const float* __restrict__ p2, const float* __restrict__ p3,
    const float* __restrict__ VS, const float* __restrict__ VD,
    float* __restrict__ AS, float* __restrict__ AD) {
  const int nrel = PRUNED ? 3 : R_REL;
  const int lane = threadIdx.x & 63;
  const int wv = (blockIdx.x << 2) + (threadIdx.x >> 6);
  if (wv >= nrel * N_NODES) return;
  const int rr = wv / N_NODES;
  const int n = wv - rr * N_NODES;
  const int r = PRUNED ? 3 * (rr + 1) : rr;
  const int s = PRUNED ? (rr + 1) : (r / 3);
  int d;
  if (PRUNED) {
    d = 0;
  } else {
    const int j = r - s * 3;
    d = (j < s) ? j : j + 1;  // DST_T[r]
  }
  const float* Xs = (s == 0) ? p0 : (s == 1) ? p1 : (s == 2) ? p2 : p3;
  const float* Xd = (d == 0) ? p0 : (d == 1) ? p1 : (d == 2) ? p2 : p3;
  float a_s, a_d;
  if (K == 128) {
    a_s = Xs[(size_t)n * K + lane] * VS[r * H_DIM + lane]
        + Xs[(size_t)n * K + 64 + lane] * VS[r * H_DIM + 64 + lane];
    a_d = Xd[(size_t)n * K + lane] * VD[r * H_DIM + lane]
        + Xd[(size_t)n * K + 64 + lane] * VD[r * H_DIM + 64 + lane];
  } else {
    a_s = Xs[(size_t)n * K + lane] * VS[r * H_DIM + lane];
    a_d = Xd[(size_t)n * K + lane] * VD[r * H_DIM + lane];
  }
  #pragma unroll
  for (int o = 32; o; o >>= 1) {
    a_s += __shfl_xor(a_s, o);
    a_d += __shfl_xor(a_d, o);
  }
  if (lane == 0) {
    AS[r * N_NODES + n] = a_s;
    AD[r * N_NODES + n] = a_d;
  }
}

// ---------------------------------------------------------------------------
// WE[r][i] = exp2(log2e * leaky_relu(AS[src] + AD[dst])) : unnormalized
// softmax weight per CSR edge slot. Valid because softmax is shift-invariant
// and |logit| <= ~3 here (no overflow risk without max-subtraction).
// ---------------------------------------------------------------------------
template <bool PRUNED>
__global__ void edge_w_kernel(const float* __restrict__ AS, const float* __restrict__ AD,
                              const int* __restrict__ EL, const int* __restrict__ DL,
                              float* __restrict__ WE) {
  int i = blockIdx.x * blockDim.x + threadIdx.x;
  int r = PRUNED ? 3 * (blockIdx.y + 1) : blockIdx.y;
  if (i >= E_EDGES) return;
  float e = AS[r * N_NODES + EL[r * E_EDGES + i]] + AD[r * N_NODES + DL[r * E_EDGES + i]];
  e = (e > 0.f) ? e : 0.2f * e;
  WE[r * E_EDGES + i] = exp2f(1.44269504f * e);
}

// ---------------------------------------------------------------------------
// Per (dst_type, node): weighted aggregation over the 3 incoming relations
// + bias + ReLU. One wave per node; lane owns cols {2*lane, 2*lane+1} so the
// per-edge XS row read is a single float2. Weights precomputed in WE.
// ---------------------------------------------------------------------------
__global__ __launch_bounds__(256) void gather_kernel(
    const float* __restrict__ XS, const float* __restrict__ WE,
    const int* __restrict__ off, const int* __restrict__ EL,
    const float* __restrict__ bias, float* __restrict__ Xout) {
  const int lane = threadIdx.x & 63;
  const int node = (blockIdx.x << 2) + (threadIdx.x >> 6);
  const int t = blockIdx.y;  // dst type
  float acc0 = 0.f, acc1 = 0.f;
  #pragma unroll
  for (int j2 = 0; j2 < 3; ++j2) {
    const int s = (j2 < t) ? j2 : j2 + 1;            // src type
    const int r = s * 3 + ((t < s) ? t : t - 1);     // relation id with dst==t
    float2 bv = *(const float2*)(bias + r * H_DIM + 2 * lane);
    acc0 += bv.x;
    acc1 += bv.y;
    const int beg = off[r * (N_NODES + 1) + node];
    const int end = off[r * (N_NODES + 1) + node + 1];
    if (beg == end) continue;
    const float* weR = WE + (size_t)r * E_EDGES;
    const int* elR = EL + (size_t)r * E_EDGES;
    const float* xsR = XS + (size_t)r * N_NODES * H_DIM;
    float den = 0.f, a0 = 0.f, a1 = 0.f;
    for (int base = beg; base < end; base += 64) {
      int i = base + lane;
      float w = 0.f;
      int src = 0;
      if (i < end) {
        w = weR[i];
        src = elR[i];
      }
      float ws = w;
      #pragma unroll
      for (int o = 32; o; o >>= 1) ws += __shfl_xor(ws, o);
      den += ws;
      int nv = min(64, end - base);
      int j = 0;
      for (; j + 1 < nv; j += 2) {
        float wj0 = __shfl(w, j);
        float wj1 = __shfl(w, j + 1);
        int sj0 = __shfl(src, j);
        int sj1 = __shfl(src, j + 1);
        float2 x0 = *(const float2*)(xsR + (size_t)sj0 * H_DIM + 2 * lane);
        float2 x1 = *(const float2*)(xsR + (size_t)sj1 * H_DIM + 2 * lane);
        a0 = fmaf(wj0, x0.x, a0);
        a1 = fmaf(wj0, x0.y, a1);
        a0 = fmaf(wj1, x1.x, a0);
        a1 = fmaf(wj1, x1.y, a1);
      }
      if (j < nv) {
        float wj = __shfl(w, j);
        int sj = __shfl(src, j);
        float2 x0 = *(const float2*)(xsR + (size_t)sj * H_DIM + 2 * lane);
        a0 = fmaf(wj, x0.x, a0);
        a1 = fmaf(wj, x0.y, a1);
      }
    }
    float inv = 1.f / den;
    acc0 = fmaf(a0, inv, acc0);
    acc1 = fmaf(a1, inv, acc1);
  }
  acc0 = fmaxf(acc0, 0.f);
  acc1 = fmaxf(acc1, 0.f);
  float2 ov = {acc0, acc1};
  *(float2*)(Xout + ((size_t)t * N_NODES + node) * H_DIM + 2 * lane) = ov;
}

// ---------------------------------------------------------------------------
// out = X2[state] @ lin_w + lin_b : [N,128]@[128,64]; wave per node, lane=col
// ---------------------------------------------------------------------------
__global__ __launch_bounds__(256) void final_kernel(
    const float* __restrict__ X, const float* __restrict__ LW,
    const float* __restrict__ LB, float* __restrict__ out) {
  const int lane = threadIdx.x & 63;
  const int node = (blockIdx.x << 2) + (threadIdx.x >> 6);
  float xlo = X[(size_t)node * H_DIM + lane];
  float xhi = X[(size_t)node * H_DIM + 64 + lane];
  float acc = LB[lane];
  #pragma unroll
  for (int k = 0; k < 64; ++k) acc = fmaf(__shfl(xlo, k), LW[k * OUT_DIM + lane], acc);
  #pragma unroll
  for (int k = 0; k < 64; ++k) acc = fmaf(__shfl(xhi, k), LW[(64 + k) * OUT_DIM + lane], acc);
  out[(size_t)node * OUT_DIM + lane] = acc;
}

// ---------------------------------------------------------------------------
extern "C" void kernel_launch(void* const* d_in, const int* in_sizes, int n_in,
                              void* d_out, int out_size, void* d_ws, size_t ws_size,
                              hipStream_t stream) {
  (void)in_sizes; (void)n_in; (void)out_size; (void)ws_size;
  const float* x_state = (const float*)d_in[0];
  const float* x_action = (const float*)d_in[1];
  const float* x_bg = (const float*)d_in[2];
  const float* x_tt = (const float*)d_in[3];
  const int* EI = (const int*)d_in[4];
  const float* Wsrc0 = (const float*)d_in[5];
  const float* Wdst0 = (const float*)d_in[6];
  const float* asrc0 = (const float*)d_in[7];
  const float* adst0 = (const float*)d_in[8];
  const float* b0 = (const float*)d_in[9];
  const float* Wsrc1 = (const float*)d_in[10];
  const float* Wdst1 = (const float*)d_in[11];
  const float* asrc1 = (const float*)d_in[12];
  const float* adst1 = (const float*)d_in[13];
  const float* b1 = (const float*)d_in[14];
  const float* lin_w = (const float*)d_in[15];
  const float* lin_b = (const float*)d_in[16];
  float* out = (float*)d_out;

  char* p = (char*)d_ws;
  auto carve = [&](size_t bytes) -> void* {
    void* q = (void*)p;
    p += (bytes + 255) & ~(size_t)255;
    return q;
  };
  float* XS = (float*)carve(sizeof(float) * (size_t)R_REL * N_NODES * H_DIM);
  float* Xa = (float*)carve(sizeof(float) * (size_t)4 * N_NODES * H_DIM);
  float* Xb = (float*)carve(sizeof(float) * (size_t)N_NODES * H_DIM);  // state only
  float* AS = (float*)carve(sizeof(float) * (size_t)R_REL * N_NODES);
  float* AD = (float*)carve(sizeof(float) * (size_t)R_REL * N_NODES);
  float* WE = (float*)carve(sizeof(float) * (size_t)R_REL * E_EDGES);
  float* VS = (float*)carve(sizeof(float) * (size_t)R_REL * H_DIM);
  float* VD = (float*)carve(sizeof(float) * (size_t)R_REL * H_DIM);
  int* CNT = (int*)carve(sizeof(int) * (size_t)R_REL * N_NODES);
  int* OFF = (int*)carve(sizeof(int) * (size_t)R_REL * (N_NODES + 1));
  int* EL = (int*)carve(sizeof(int) * (size_t)R_REL * E_EDGES);
  int* DL = (int*)carve(sizeof(int) * (size_t)R_REL * E_EDGES);

  // CSR build (shared by both layers)
  hipMemsetAsync(CNT, 0, sizeof(int) * (size_t)R_REL * N_NODES, stream);
  dim3 ge((E_EDGES + 255) / 256, R_REL);
  hist_kernel<<<ge, 256, 0, stream>>>(EI, CNT);
  scan_kernel<<<R_REL, 1024, 0, stream>>>(CNT, OFF);
  fill_kernel<<<ge, 256, 0, stream>>>(EI, CNT, EL, DL);

  // ---- layer 0 (K = 64, all 12 relations) ----
  vcomp_kernel<IN_DIM><<<R_REL, IN_DIM, 0, stream>>>(Wsrc0, asrc0, Wdst0, adst0, VS, VD);
  gemm_xs_kernel<IN_DIM, false><<<dim3((N_NODES + 127) / 128, R_REL), 256, 0, stream>>>(
      x_state, x_action, x_bg, x_tt, Wsrc0, XS);
  attn_coef_kernel<IN_DIM, false><<<(R_REL * N_NODES) / 4, 256, 0, stream>>>(
      x_state, x_action, x_bg, x_tt, VS, VD, AS, AD);
  edge_w_kernel<false><<<dim3((E_EDGES + 255) / 256, R_REL), 256, 0, stream>>>(
      AS, AD, EL, DL, WE);
  gather_kernel<<<dim3(N_NODES / 4, 4), 256, 0, stream>>>(XS, WE, OFF, EL, b0, Xa);

  // ---- layer 1 (K = 128, only relations into 'state': r = 3,6,9) ----
  const float* a0p = Xa;
  const float* a1p = Xa + (size_t)N_NODES * H_DIM;
  const float* a2p = Xa + (size_t)2 * N_NODES * H_DIM;
  const float* a3p = Xa + (size_t)3 * N_NODES * H_DIM;
  vcomp_kernel<H_DIM><<<R_REL, H_DIM, 0, stream>>>(Wsrc1, asrc1, Wdst1, adst1, VS, VD);
  gemm_xs_kernel<H_DIM, true><<<dim3((N_NODES + 127) / 128, 3), 256, 0, stream>>>(
      a0p, a1p, a2p, a3p, Wsrc1, XS);
  attn_coef_kernel<H_DIM, true><<<(3 * N_NODES) / 4, 256, 0, stream>>>(
      a0p, a1p, a2p, a3p, VS, VD, AS, AD);
  edge_w_kernel<true><<<dim3((E_EDGES + 255) / 256, 3), 256, 0, stream>>>(
      AS, AD, EL, DL, WE);
  gather_kernel<<<dim3(N_NODES / 4, 1), 256, 0, stream>>>(XS, WE, OFF, EL, b1, Xb);

  // ---- final linear on 'state' ----
  final_kernel<<<N_NODES / 4, 256, 0, stream>>>(Xb, lin_w, lin_b, out);
}

// Round 11
// 398.298 us; speedup vs baseline: 1.0249x; 1.0249x over previous
//
#include <hip/hip_runtime.h>
#include <cfloat>
#include <cmath>

#define N_NODES 10000
#define E_EDGES 80000
#define R_REL   12
#define H_DIM   128
#define IN_DIM  64
#define OUT_DIM 64

// ---------------------------------------------------------------------------
// CSR build (by destination node, per relation). EL stores SRC node ids.
// ---------------------------------------------------------------------------
__global__ void hist_kernel(const int* __restrict__ EI, int* __restrict__ cnt) {
  int e = blockIdx.x * blockDim.x + threadIdx.x;
  int r = blockIdx.y;
  if (e >= E_EDGES) return;
  int dst = EI[(2 * r + 1) * E_EDGES + e];
  atomicAdd(&cnt[r * N_NODES + dst], 1);
}

// Block-parallel exclusive scan: one 1024-thread block per relation.
#define SCAN_E 10
__global__ __launch_bounds__(1024) void scan_kernel(int* __restrict__ cnt,
                                                    int* __restrict__ off) {
  const int r = blockIdx.x;
  const int t = threadIdx.x;
  const int lane = t & 63, wv = t >> 6;  // 16 waves
  __shared__ int wsum[16];

  const int base = t * SCAN_E;
  int v[SCAN_E];
  int s = 0;
  #pragma unroll
  for (int k = 0; k < SCAN_E; ++k) {
    int i = base + k;
    v[k] = (i < N_NODES) ? cnt[r * N_NODES + i] : 0;
    s += v[k];
  }
  int incl = s;
  #pragma unroll
  for (int o = 1; o < 64; o <<= 1) {
    int u = __shfl_up(incl, o);
    if (lane >= o) incl += u;
  }
  if (lane == 63) wsum[wv] = incl;
  __syncthreads();
  if (wv == 0) {
    int ws = (lane < 16) ? wsum[lane] : 0;
    int wi = ws;
    #pragma unroll
    for (int o = 1; o < 16; o <<= 1) {
      int u = __shfl_up(wi, o);
      if (lane >= o) wi += u;
    }
    if (lane < 16) wsum[lane] = wi - ws;  // exclusive wave prefix
  }
  __syncthreads();
  int run = wsum[wv] + incl - s;
  #pragma unroll
  for (int k = 0; k < SCAN_E; ++k) {
    int i = base + k;
    if (i < N_NODES) {
      off[r * (N_NODES + 1) + i] = run;
      cnt[r * N_NODES + i] = run;  // becomes fill cursor
      run += v[k];
    }
  }
  if (t == 1023) off[r * (N_NODES + 1) + N_NODES] = run;
}

__global__ void fill_kernel(const int* __restrict__ EI, int* __restrict__ cur,
                            int* __restrict__ EL) {
  int e = blockIdx.x * blockDim.x + threadIdx.x;
  int r = blockIdx.y;
  if (e >= E_EDGES) return;
  int dst = EI[(2 * r + 1) * E_EDGES + e];
  int src = EI[(2 * r + 0) * E_EDGES + e];
  int pos = atomicAdd(&cur[r * N_NODES + dst], 1);
  EL[r * E_EDGES + pos] = src;
}

// ---------------------------------------------------------------------------
// vsrc[r] = Wsrc[r] @ asrc[r], vdst[r] = Wdst[r] @ adst[r]   (tiny)
// ---------------------------------------------------------------------------
template <int K>
__global__ void vcomp_kernel(const float* __restrict__ Wsrc, const float* __restrict__ asrc,
                             const float* __restrict__ Wdst, const float* __restrict__ adst,
                             float* __restrict__ VS, float* __restrict__ VD) {
  const int r = blockIdx.x;
  const int k = threadIdx.x;  // K threads
  const float* w1 = Wsrc + ((size_t)r * K + k) * H_DIM;
  const float* w2 = Wdst + ((size_t)r * K + k) * H_DIM;
  const float* a1 = asrc + r * H_DIM;
  const float* a2 = adst + r * H_DIM;
  float s1 = 0.f, s2 = 0.f;
  for (int h = 0; h < H_DIM; ++h) {
    s1 = fmaf(w1[h], a1[h], s1);
    s2 = fmaf(w2[h], a2[h], s2);
  }
  VS[r * H_DIM + k] = s1;
  VD[r * H_DIM + k] = s2;
}

// ---------------------------------------------------------------------------
// XS[r] = X[src_type(r)] @ Wsrc[r] : [N,K]@[K,128], fp32 tiled GEMM
// ---------------------------------------------------------------------------
template <int K, bool PRUNED>
__global__ __launch_bounds__(256) void gemm_xs_kernel(
    const float* __restrict__ p0, const float* __restrict__ p1,
    const float* __restrict__ p2, const float* __restrict__ p3,
    const float* __restrict__ W,   // [R][K][H]
    float* __restrict__ XS) {      // [R][N][H]
  const int r = PRUNED ? 3 * (blockIdx.y + 1) : blockIdx.y;
  const int s = PRUNED ? (blockIdx.y + 1) : (r / 3);  // SRC_T[r]
  const float* __restrict__ X = (s == 0) ? p0 : (s == 1) ? p1 : (s == 2) ? p2 : p3;
  const int row0 = blockIdx.x * 128;
  const int tid = threadIdx.x;
  const int tx = tid & 15, ty = tid >> 4;
  __shared__ float Xst[32][132];  // [k][row], padded
  __shared__ float Ws[32][132];   // [k][col], padded

  float acc[8][8];
  #pragma unroll
  for (int i = 0; i < 8; ++i)
    #pragma unroll
    for (int j = 0; j < 8; ++j) acc[i][j] = 0.f;

  const float* Wr = W + (size_t)r * K * H_DIM;

  #pragma unroll 1
  for (int k0 = 0; k0 < K; k0 += 32) {
    #pragma unroll
    for (int p = 0; p < 4; ++p) {
      int idx = tid + p * 256;   // 0..1023 float4 slots
      int row = idx >> 3;        // 8 float4 per row
      int kq = idx & 7;
      float4 v = {0.f, 0.f, 0.f, 0.f};
      int grow = row0 + row;
      if (grow < N_NODES)
        v = *(const float4*)(X + (size_t)grow * K + k0 + kq * 4);
      Xst[kq * 4 + 0][row] = v.x;
      Xst[kq * 4 + 1][row] = v.y;
      Xst[kq * 4 + 2][row] = v.z;
      Xst[kq * 4 + 3][row] = v.w;
    }
    #pragma unroll
    for (int p = 0; p < 4; ++p) {
      int idx = tid + p * 256;
      int kk = idx >> 5;  // 32 float4 per row
      int cq = idx & 31;
      float4 v = *(const float4*)(Wr + (size_t)(k0 + kk) * H_DIM + cq * 4);
      *(float4*)&Ws[kk][cq * 4] = v;
    }
    __syncthreads();
    #pragma unroll
    for (int kk = 0; kk < 32; ++kk) {
      float a[8], b[8];
      *(float4*)&a[0] = *(float4*)&Xst[kk][ty * 8];
      *(float4*)&a[4] = *(float4*)&Xst[kk][ty * 8 + 4];
      *(float4*)&b[0] = *(float4*)&Ws[kk][tx * 8];
      *(float4*)&b[4] = *(float4*)&Ws[kk][tx * 8 + 4];
      #pragma unroll
      for (int i = 0; i < 8; ++i)
        #pragma unroll
        for (int j = 0; j < 8; ++j) acc[i][j] = fmaf(a[i], b[j], acc[i][j]);
    }
    __syncthreads();
  }
  float* outp = XS + (size_t)r * N_NODES * H_DIM;
  #pragma unroll
  for (int i = 0; i < 8; ++i) {
    int row = row0 + ty * 8 + i;
    if (row < N_NODES) {
      *(float4*)(outp + (size_t)row * H_DIM + tx * 8) = *(float4*)&acc[i][0];
      *(float4*)(outp + (size_t)row * H_DIM + tx * 8 + 4) = *(float4*)&acc[i][4];
    }
  }
}

// ---------------------------------------------------------------------------
// AS[r][n] = X[src_t][n] . VS[r] ;  AD[r][n] = X[dst_t][n] . VD[r]
// ---------------------------------------------------------------------------
template <int K, bool PRUNED>
__global__ __launch_bounds__(256) void attn_coef_kernel(
    const float* __restrict__ p0, const float* __restrict__ p1,
    const float* __restrict__ p2, const float* __restrict__ p3,
    const float* __restrict__ VS, const float* __restrict__ VD,
    float* __restrict__ AS, float* __restrict__ AD) {
  const int nrel = PRUNED ? 3 : R_REL;
  const int lane = threadIdx.x & 63;
  const int wv = (blockIdx.x << 2) + (threadIdx.x >> 6);
  if (wv >= nrel * N_NODES) return;
  const int rr = wv / N_NODES;
  const int n = wv - rr * N_NODES;
  const int r = PRUNED ? 3 * (rr + 1) : rr;
  const int s = PRUNED ? (rr + 1) : (r / 3);
  int d;
  if (PRUNED) {
    d = 0;
  } else {
    const int j = r - s * 3;
    d = (j < s) ? j : j + 1;  // DST_T[r]
  }
  const float* Xs = (s == 0) ? p0 : (s == 1) ? p1 : (s == 2) ? p2 : p3;
  const float* Xd = (d == 0) ? p0 : (d == 1) ? p1 : (d == 2) ? p2 : p3;
  float a_s, a_d;
  if (K == 128) {
    a_s = Xs[(size_t)n * K + lane] * VS[r * H_DIM + lane]
        + Xs[(size_t)n * K + 64 + lane] * VS[r * H_DIM + 64 + lane];
    a_d = Xd[(size_t)n * K + lane] * VD[r * H_DIM + lane]
        + Xd[(size_t)n * K + 64 + lane] * VD[r * H_DIM + 64 + lane];
  } else {
    a_s = Xs[(size_t)n * K + lane] * VS[r * H_DIM + lane];
    a_d = Xd[(size_t)n * K + lane] * VD[r * H_DIM + lane];
  }
  #pragma unroll
  for (int o = 32; o; o >>= 1) {
    a_s += __shfl_xor(a_s, o);
    a_d += __shfl_xor(a_d, o);
  }
  if (lane == 0) {
    AS[r * N_NODES + n] = a_s;
    AD[r * N_NODES + n] = a_d;
  }
}

// ---------------------------------------------------------------------------
// ASE[r][i] = AS[r][EL[r][i]] : attention src-logits gathered into CSR edge
// order, so the hot per-node loops read them coalesced.
// ---------------------------------------------------------------------------
template <bool PRUNED>
__global__ void edge_as_kernel(const float* __restrict__ AS, const int* __restrict__ EL,
                               float* __restrict__ ASE) {
  int i = blockIdx.x * blockDim.x + threadIdx.x;
  int r = PRUNED ? 3 * (blockIdx.y + 1) : blockIdx.y;
  if (i >= E_EDGES) return;
  ASE[r * E_EDGES + i] = AS[r * N_NODES + EL[r * E_EDGES + i]];
}

// ---------------------------------------------------------------------------
// Per (dst_type, node): softmax-weighted aggregation over the 3 incoming
// relations + bias + ReLU. One wave per node; lane owns cols {2*lane,
// 2*lane+1} (single float2 per edge-row). Unnormalized weights computed
// in-lane: w = exp2(log2e * leaky_relu(ASE[i] + AD[node])) — softmax is
// shift-invariant and |logit| is small, so no max pass needed.
// ---------------------------------------------------------------------------
__global__ __launch_bounds__(256) void gather_kernel(
    const float* __restrict__ XS, const float* __restrict__ ASE,
    const float* __restrict__ AD, const int* __restrict__ off,
    const int* __restrict__ EL, const float* __restrict__ bias,
    float* __restrict__ Xout) {
  const int lane = threadIdx.x & 63;
  const int node = (blockIdx.x << 2) + (threadIdx.x >> 6);
  const int t = blockIdx.y;  // dst type
  float acc0 = 0.f, acc1 = 0.f;
  #pragma unroll
  for (int j2 = 0; j2 < 3; ++j2) {
    const int s = (j2 < t) ? j2 : j2 + 1;            // src type
    const int r = s * 3 + ((t < s) ? t : t - 1);     // relation id with dst==t
    float2 bv = *(const float2*)(bias + r * H_DIM + 2 * lane);
    acc0 += bv.x;
    acc1 += bv.y;
    const int beg = off[r * (N_NODES + 1) + node];
    const int end = off[r * (N_NODES + 1) + node + 1];
    if (beg == end) continue;
    const float ad = AD[r * N_NODES + node];
    const float* aseR = ASE + (size_t)r * E_EDGES;
    const int* elR = EL + (size_t)r * E_EDGES;
    const float* xsR = XS + (size_t)r * N_NODES * H_DIM;
    float den = 0.f, a0 = 0.f, a1 = 0.f;
    for (int base = beg; base < end; base += 64) {
      int i = base + lane;
      float w = 0.f;
      int src = 0;
      if (i < end) {
        float e = aseR[i] + ad;
        e = (e > 0.f) ? e : 0.2f * e;
        w = exp2f(1.44269504f * e);
        src = elR[i];
      }
      float ws = w;
      #pragma unroll
      for (int o = 32; o; o >>= 1) ws += __shfl_xor(ws, o);
      den += ws;
      int nv = min(64, end - base);
      int j = 0;
      for (; j + 1 < nv; j += 2) {
        float wj0 = __shfl(w, j);
        float wj1 = __shfl(w, j + 1);
        int sj0 = __shfl(src, j);
        int sj1 = __shfl(src, j + 1);
        float2 x0 = *(const float2*)(xsR + (size_t)sj0 * H_DIM + 2 * lane);
        float2 x1 = *(const float2*)(xsR + (size_t)sj1 * H_DIM + 2 * lane);
        a0 = fmaf(wj0, x0.x, a0);
        a1 = fmaf(wj0, x0.y, a1);
        a0 = fmaf(wj1, x1.x, a0);
        a1 = fmaf(wj1, x1.y, a1);
      }
      if (j < nv) {
        float wj = __shfl(w, j);
        int sj = __shfl(src, j);
        float2 x0 = *(const float2*)(xsR + (size_t)sj * H_DIM + 2 * lane);
        a0 = fmaf(wj, x0.x, a0);
        a1 = fmaf(wj, x0.y, a1);
      }
    }
    float inv = 1.f / den;
    acc0 = fmaf(a0, inv, acc0);
    acc1 = fmaf(a1, inv, acc1);
  }
  acc0 = fmaxf(acc0, 0.f);
  acc1 = fmaxf(acc1, 0.f);
  float2 ov = {acc0, acc1};
  *(float2*)(Xout + ((size_t)t * N_NODES + node) * H_DIM + 2 * lane) = ov;
}

// ---------------------------------------------------------------------------
// out = X2[state] @ lin_w + lin_b : [N,128]@[128,64]; wave per node, lane=col
// ---------------------------------------------------------------------------
__global__ __launch_bounds__(256) void final_kernel(
    const float* __restrict__ X, const float* __restrict__ LW,
    const float* __restrict__ LB, float* __restrict__ out) {
  const int lane = threadIdx.x & 63;
  const int node = (blockIdx.x << 2) + (threadIdx.x >> 6);
  float xlo = X[(size_t)node * H_DIM + lane];
  float xhi = X[(size_t)node * H_DIM + 64 + lane];
  float acc = LB[lane];
  #pragma unroll
  for (int k = 0; k < 64; ++k) acc = fmaf(__shfl(xlo, k), LW[k * OUT_DIM + lane], acc);
  #pragma unroll
  for (int k = 0; k < 64; ++k) acc = fmaf(__shfl(xhi, k), LW[(64 + k) * OUT_DIM + lane], acc);
  out[(size_t)node * OUT_DIM + lane] = acc;
}

// ---------------------------------------------------------------------------
extern "C" void kernel_launch(void* const* d_in, const int* in_sizes, int n_in,
                              void* d_out, int out_size, void* d_ws, size_t ws_size,
                              hipStream_t stream) {
  (void)in_sizes; (void)n_in; (void)out_size; (void)ws_size;
  const float* x_state = (const float*)d_in[0];
  const float* x_action = (const float*)d_in[1];
  const float* x_bg = (const float*)d_in[2];
  const float* x_tt = (const float*)d_in[3];
  const int* EI = (const int*)d_in[4];
  const float* Wsrc0 = (const float*)d_in[5];
  const float* Wdst0 = (const float*)d_in[6];
  const float* asrc0 = (const float*)d_in[7];
  const float* adst0 = (const float*)d_in[8];
  const float* b0 = (const float*)d_in[9];
  const float* Wsrc1 = (const float*)d_in[10];
  const float* Wdst1 = (const float*)d_in[11];
  const float* asrc1 = (const float*)d_in[12];
  const float* adst1 = (const float*)d_in[13];
  const float* b1 = (const float*)d_in[14];
  const float* lin_w = (const float*)d_in[15];
  const float* lin_b = (const float*)d_in[16];
  float* out = (float*)d_out;

  char* p = (char*)d_ws;
  auto carve = [&](size_t bytes) -> void* {
    void* q = (void*)p;
    p += (bytes + 255) & ~(size_t)255;
    return q;
  };
  float* XS = (float*)carve(sizeof(float) * (size_t)R_REL * N_NODES * H_DIM);
  float* Xa = (float*)carve(sizeof(float) * (size_t)4 * N_NODES * H_DIM);
  float* Xb = (float*)carve(sizeof(float) * (size_t)N_NODES * H_DIM);  // state only
  float* AS = (float*)carve(sizeof(float) * (size_t)R_REL * N_NODES);
  float* AD = (float*)carve(sizeof(float) * (size_t)R_REL * N_NODES);
  float* ASE = (float*)carve(sizeof(float) * (size_t)R_REL * E_EDGES);
  float* VS = (float*)carve(sizeof(float) * (size_t)R_REL * H_DIM);
  float* VD = (float*)carve(sizeof(float) * (size_t)R_REL * H_DIM);
  int* CNT = (int*)carve(sizeof(int) * (size_t)R_REL * N_NODES);
  int* OFF = (int*)carve(sizeof(int) * (size_t)R_REL * (N_NODES + 1));
  int* EL = (int*)carve(sizeof(int) * (size_t)R_REL * E_EDGES);

  // CSR build (shared by both layers)
  hipMemsetAsync(CNT, 0, sizeof(int) * (size_t)R_REL * N_NODES, stream);
  dim3 ge((E_EDGES + 255) / 256, R_REL);
  hist_kernel<<<ge, 256, 0, stream>>>(EI, CNT);
  scan_kernel<<<R_REL, 1024, 0, stream>>>(CNT, OFF);
  fill_kernel<<<ge, 256, 0, stream>>>(EI, CNT, EL);

  // ---- layer 0 (K = 64, all 12 relations) ----
  vcomp_kernel<IN_DIM><<<R_REL, IN_DIM, 0, stream>>>(Wsrc0, asrc0, Wdst0, adst0, VS, VD);
  gemm_xs_kernel<IN_DIM, false><<<dim3((N_NODES + 127) / 128, R_REL), 256, 0, stream>>>(
      x_state, x_action, x_bg, x_tt, Wsrc0, XS);
  attn_coef_kernel<IN_DIM, false><<<(R_REL * N_NODES) / 4, 256, 0, stream>>>(
      x_state, x_action, x_bg, x_tt, VS, VD, AS, AD);
  edge_as_kernel<false><<<dim3((E_EDGES + 255) / 256, R_REL), 256, 0, stream>>>(AS, EL, ASE);
  gather_kernel<<<dim3(N_NODES / 4, 4), 256, 0, stream>>>(XS, ASE, AD, OFF, EL, b0, Xa);

  // ---- layer 1 (K = 128, only relations into 'state': r = 3,6,9) ----
  const float* a0p = Xa;
  const float* a1p = Xa + (size_t)N_NODES * H_DIM;
  const float* a2p = Xa + (size_t)2 * N_NODES * H_DIM;
  const float* a3p = Xa + (size_t)3 * N_NODES * H_DIM;
  vcomp_kernel<H_DIM><<<R_REL, H_DIM, 0, stream>>>(Wsrc1, asrc1, Wdst1, adst1, VS, VD);
  gemm_xs_kernel<H_DIM, true><<<dim3((N_NODES + 127) / 128, 3), 256, 0, stream>>>(
      a0p, a1p, a2p, a3p, Wsrc1, XS);
  attn_coef_kernel<H_DIM, true><<<(3 * N_NODES) / 4, 256, 0, stream>>>(
      a0p, a1p, a2p, a3p, VS, VD, AS, AD);
  edge_as_kernel<true><<<dim3((E_EDGES + 255) / 256, 3), 256, 0, stream>>>(AS, EL, ASE);
  gather_kernel<<<dim3(N_NODES / 4, 1), 256, 0, stream>>>(XS, ASE, AD, OFF, EL, b1, Xb);

  // ---- final linear on 'state' ----
  final_kernel<<<N_NODES / 4, 256, 0, stream>>>(Xb, lin_w, lin_b, out);
}

// Round 12
// 375.919 us; speedup vs baseline: 1.0859x; 1.0595x over previous
//
#include <hip/hip_runtime.h>
#include <hip/hip_fp16.h>
#include <cfloat>
#include <cmath>

#define N_NODES 10000
#define E_EDGES 80000
#define R_REL   12
#define H_DIM   128
#define IN_DIM  64
#define OUT_DIM 64

// ---------------------------------------------------------------------------
// CSR build (by destination node, per relation). EL stores SRC node ids.
// ---------------------------------------------------------------------------
__global__ void hist_kernel(const int* __restrict__ EI, int* __restrict__ cnt) {
  int e = blockIdx.x * blockDim.x + threadIdx.x;
  int r = blockIdx.y;
  if (e >= E_EDGES) return;
  int dst = EI[(2 * r + 1) * E_EDGES + e];
  atomicAdd(&cnt[r * N_NODES + dst], 1);
}

// Block-parallel exclusive scan: one 1024-thread block per relation.
#define SCAN_E 10
__global__ __launch_bounds__(1024) void scan_kernel(int* __restrict__ cnt,
                                                    int* __restrict__ off) {
  const int r = blockIdx.x;
  const int t = threadIdx.x;
  const int lane = t & 63, wv = t >> 6;  // 16 waves
  __shared__ int wsum[16];

  const int base = t * SCAN_E;
  int v[SCAN_E];
  int s = 0;
  #pragma unroll
  for (int k = 0; k < SCAN_E; ++k) {
    int i = base + k;
    v[k] = (i < N_NODES) ? cnt[r * N_NODES + i] : 0;
    s += v[k];
  }
  int incl = s;
  #pragma unroll
  for (int o = 1; o < 64; o <<= 1) {
    int u = __shfl_up(incl, o);
    if (lane >= o) incl += u;
  }
  if (lane == 63) wsum[wv] = incl;
  __syncthreads();
  if (wv == 0) {
    int ws = (lane < 16) ? wsum[lane] : 0;
    int wi = ws;
    #pragma unroll
    for (int o = 1; o < 16; o <<= 1) {
      int u = __shfl_up(wi, o);
      if (lane >= o) wi += u;
    }
    if (lane < 16) wsum[lane] = wi - ws;  // exclusive wave prefix
  }
  __syncthreads();
  int run = wsum[wv] + incl - s;
  #pragma unroll
  for (int k = 0; k < SCAN_E; ++k) {
    int i = base + k;
    if (i < N_NODES) {
      off[r * (N_NODES + 1) + i] = run;
      cnt[r * N_NODES + i] = run;  // becomes fill cursor
      run += v[k];
    }
  }
  if (t == 1023) off[r * (N_NODES + 1) + N_NODES] = run;
}

__global__ void fill_kernel(const int* __restrict__ EI, int* __restrict__ cur,
                            int* __restrict__ EL) {
  int e = blockIdx.x * blockDim.x + threadIdx.x;
  int r = blockIdx.y;
  if (e >= E_EDGES) return;
  int dst = EI[(2 * r + 1) * E_EDGES + e];
  int src = EI[(2 * r + 0) * E_EDGES + e];
  int pos = atomicAdd(&cur[r * N_NODES + dst], 1);
  EL[r * E_EDGES + pos] = src;
}

// ---------------------------------------------------------------------------
// vsrc[r] = Wsrc[r] @ asrc[r], vdst[r] = Wdst[r] @ adst[r]   (tiny)
// ---------------------------------------------------------------------------
template <int K>
__global__ void vcomp_kernel(const float* __restrict__ Wsrc, const float* __restrict__ asrc,
                             const float* __restrict__ Wdst, const float* __restrict__ adst,
                             float* __restrict__ VS, float* __restrict__ VD) {
  const int r = blockIdx.x;
  const int k = threadIdx.x;  // K threads
  const float* w1 = Wsrc + ((size_t)r * K + k) * H_DIM;
  const float* w2 = Wdst + ((size_t)r * K + k) * H_DIM;
  const float* a1 = asrc + r * H_DIM;
  const float* a2 = adst + r * H_DIM;
  float s1 = 0.f, s2 = 0.f;
  for (int h = 0; h < H_DIM; ++h) {
    s1 = fmaf(w1[h], a1[h], s1);
    s2 = fmaf(w2[h], a2[h], s2);
  }
  VS[r * H_DIM + k] = s1;
  VD[r * H_DIM + k] = s2;
}

// ---------------------------------------------------------------------------
// XS[r] = X[src_type(r)] @ Wsrc[r] : [N,K]@[K,128], fp32 tiled GEMM.
// Output stored as fp16 (halves the random-fetch bytes in gather, which R11
// counters showed is bytes-bound: 196 MB @ 3.3 TB/s, VALUBusy 42%).
// ---------------------------------------------------------------------------
template <int K, bool PRUNED>
__global__ __launch_bounds__(256) void gemm_xs_kernel(
    const float* __restrict__ p0, const float* __restrict__ p1,
    const float* __restrict__ p2, const float* __restrict__ p3,
    const float* __restrict__ W,   // [R][K][H]
    __half* __restrict__ XS) {     // [R][N][H] fp16
  const int r = PRUNED ? 3 * (blockIdx.y + 1) : blockIdx.y;
  const int s = PRUNED ? (blockIdx.y + 1) : (r / 3);  // SRC_T[r]
  const float* __restrict__ X = (s == 0) ? p0 : (s == 1) ? p1 : (s == 2) ? p2 : p3;
  const int row0 = blockIdx.x * 128;
  const int tid = threadIdx.x;
  const int tx = tid & 15, ty = tid >> 4;
  __shared__ float Xst[32][132];  // [k][row], padded
  __shared__ float Ws[32][132];   // [k][col], padded

  float acc[8][8];
  #pragma unroll
  for (int i = 0; i < 8; ++i)
    #pragma unroll
    for (int j = 0; j < 8; ++j) acc[i][j] = 0.f;

  const float* Wr = W + (size_t)r * K * H_DIM;

  #pragma unroll 1
  for (int k0 = 0; k0 < K; k0 += 32) {
    #pragma unroll
    for (int p = 0; p < 4; ++p) {
      int idx = tid + p * 256;   // 0..1023 float4 slots
      int row = idx >> 3;        // 8 float4 per row
      int kq = idx & 7;
      float4 v = {0.f, 0.f, 0.f, 0.f};
      int grow = row0 + row;
      if (grow < N_NODES)
        v = *(const float4*)(X + (size_t)grow * K + k0 + kq * 4);
      Xst[kq * 4 + 0][row] = v.x;
      Xst[kq * 4 + 1][row] = v.y;
      Xst[kq * 4 + 2][row] = v.z;
      Xst[kq * 4 + 3][row] = v.w;
    }
    #pragma unroll
    for (int p = 0; p < 4; ++p) {
      int idx = tid + p * 256;
      int kk = idx >> 5;  // 32 float4 per row
      int cq = idx & 31;
      float4 v = *(const float4*)(Wr + (size_t)(k0 + kk) * H_DIM + cq * 4);
      *(float4*)&Ws[kk][cq * 4] = v;
    }
    __syncthreads();
    #pragma unroll
    for (int kk = 0; kk < 32; ++kk) {
      float a[8], b[8];
      *(float4*)&a[0] = *(float4*)&Xst[kk][ty * 8];
      *(float4*)&a[4] = *(float4*)&Xst[kk][ty * 8 + 4];
      *(float4*)&b[0] = *(float4*)&Ws[kk][tx * 8];
      *(float4*)&b[4] = *(float4*)&Ws[kk][tx * 8 + 4];
      #pragma unroll
      for (int i = 0; i < 8; ++i)
        #pragma unroll
        for (int j = 0; j < 8; ++j) acc[i][j] = fmaf(a[i], b[j], acc[i][j]);
    }
    __syncthreads();
  }
  __half* outp = XS + (size_t)r * N_NODES * H_DIM;
  #pragma unroll
  for (int i = 0; i < 8; ++i) {
    int row = row0 + ty * 8 + i;
    if (row < N_NODES) {
      union { __half2 h[4]; float4 f; } u;
      u.h[0] = __floats2half2_rn(acc[i][0], acc[i][1]);
      u.h[1] = __floats2half2_rn(acc[i][2], acc[i][3]);
      u.h[2] = __floats2half2_rn(acc[i][4], acc[i][5]);
      u.h[3] = __floats2half2_rn(acc[i][6], acc[i][7]);
      // byte offset (row*128 + tx*8)*2 is 16B-aligned
      *(float4*)(outp + (size_t)row * H_DIM + tx * 8) = u.f;
    }
  }
}

// ---------------------------------------------------------------------------
// AS[r][n] = X[src_t][n] . VS[r] ;  AD[r][n] = X[dst_t][n] . VD[r]
// (reads the fp32 node features, unchanged)
// ---------------------------------------------------------------------------
template <int K, bool PRUNED>
__global__ __launch_bounds__(256) void attn_coef_kernel(
    const float* __restrict__ p0, const float* __restrict__ p1,
    const float* __restrict__ p2, const float* __restrict__ p3,
    const float* __restrict__ VS, const float* __restrict__ VD,
    float* __restrict__ AS, float* __restrict__ AD) {
  const int nrel = PRUNED ? 3 : R_REL;
  const int lane = threadIdx.x & 63;
  const int wv = (blockIdx.x << 2) + (threadIdx.x >> 6);
  if (wv >= nrel * N_NODES) return;
  const int rr = wv / N_NODES;
  const int n = wv - rr * N_NODES;
  const int r = PRUNED ? 3 * (rr + 1) : rr;
  const int s = PRUNED ? (rr + 1) : (r / 3);
  int d;
  if (PRUNED) {
    d = 0;
  } else {
    const int j = r - s * 3;
    d = (j < s) ? j : j + 1;  // DST_T[r]
  }
  const float* Xs = (s == 0) ? p0 : (s == 1) ? p1 : (s == 2) ? p2 : p3;
  const float* Xd = (d == 0) ? p0 : (d == 1) ? p1 : (d == 2) ? p2 : p3;
  float a_s, a_d;
  if (K == 128) {
    a_s = Xs[(size_t)n * K + lane] * VS[r * H_DIM + lane]
        + Xs[(size_t)n * K + 64 + lane] * VS[r * H_DIM + 64 + lane];
    a_d = Xd[(size_t)n * K + lane] * VD[r * H_DIM + lane]
        + Xd[(size_t)n * K + 64 + lane] * VD[r * H_DIM + 64 + lane];
  } else {
    a_s = Xs[(size_t)n * K + lane] * VS[r * H_DIM + lane];
    a_d = Xd[(size_t)n * K + lane] * VD[r * H_DIM + lane];
  }
  #pragma unroll
  for (int o = 32; o; o >>= 1) {
    a_s += __shfl_xor(a_s, o);
    a_d += __shfl_xor(a_d, o);
  }
  if (lane == 0) {
    AS[r * N_NODES + n] = a_s;
    AD[r * N_NODES + n] = a_d;
  }
}

// ---------------------------------------------------------------------------
// ASE[r][i] = AS[r][EL[r][i]] : attention src-logits gathered into CSR edge
// order, so the hot per-node loops read them coalesced.
// ---------------------------------------------------------------------------
template <bool PRUNED>
__global__ void edge_as_kernel(const float* __restrict__ AS, const int* __restrict__ EL,
                               float* __restrict__ ASE) {
  int i = blockIdx.x * blockDim.x + threadIdx.x;
  int r = PRUNED ? 3 * (blockIdx.y + 1) : blockIdx.y;
  if (i >= E_EDGES) return;
  ASE[r * E_EDGES + i] = AS[r * N_NODES + EL[r * E_EDGES + i]];
}

// ---------------------------------------------------------------------------
// Per (dst_type, node): softmax-weighted aggregation over the 3 incoming
// relations + bias + ReLU. One wave per node; lane owns cols {2*lane,
// 2*lane+1} → one 4B __half2 per edge-row (fp16 XS halves random fetch).
// Unnormalized weights computed in-lane (shift-invariant softmax, small
// logits → no max pass).
// ---------------------------------------------------------------------------
__global__ __launch_bounds__(256) void gather_kernel(
    const __half2* __restrict__ XS, const float* __restrict__ ASE,
    const float* __restrict__ AD, const int* __restrict__ off,
    const int* __restrict__ EL, const float* __restrict__ bias,
    float* __restrict__ Xout) {
  const int lane = threadIdx.x & 63;
  const int node = (blockIdx.x << 2) + (threadIdx.x >> 6);
  const int t = blockIdx.y;  // dst type
  float acc0 = 0.f, acc1 = 0.f;
  #pragma unroll
  for (int j2 = 0; j2 < 3; ++j2) {
    const int s = (j2 < t) ? j2 : j2 + 1;            // src type
    const int r = s * 3 + ((t < s) ? t : t - 1);     // relation id with dst==t
    float2 bv = *(const float2*)(bias + r * H_DIM + 2 * lane);
    acc0 += bv.x;
    acc1 += bv.y;
    const int beg = off[r * (N_NODES + 1) + node];
    const int end = off[r * (N_NODES + 1) + node + 1];
    if (beg == end) continue;
    const float ad = AD[r * N_NODES + node];
    const float* aseR = ASE + (size_t)r * E_EDGES;
    const int* elR = EL + (size_t)r * E_EDGES;
    const __half2* xsR = XS + (size_t)r * N_NODES * (H_DIM / 2);
    float den = 0.f, a0 = 0.f, a1 = 0.f;
    for (int base = beg; base < end; base += 64) {
      int i = base + lane;
      float w = 0.f;
      int src = 0;
      if (i < end) {
        float e = aseR[i] + ad;
        e = (e > 0.f) ? e : 0.2f * e;
        w = exp2f(1.44269504f * e);
        src = elR[i];
      }
      float ws = w;
      #pragma unroll
      for (int o = 32; o; o >>= 1) ws += __shfl_xor(ws, o);
      den += ws;
      int nv = min(64, end - base);
      int j = 0;
      for (; j + 1 < nv; j += 2) {
        float wj0 = __shfl(w, j);
        float wj1 = __shfl(w, j + 1);
        int sj0 = __shfl(src, j);
        int sj1 = __shfl(src, j + 1);
        float2 x0 = __half22float2(xsR[(size_t)sj0 * (H_DIM / 2) + lane]);
        float2 x1 = __half22float2(xsR[(size_t)sj1 * (H_DIM / 2) + lane]);
        a0 = fmaf(wj0, x0.x, a0);
        a1 = fmaf(wj0, x0.y, a1);
        a0 = fmaf(wj1, x1.x, a0);
        a1 = fmaf(wj1, x1.y, a1);
      }
      if (j < nv) {
        float wj = __shfl(w, j);
        int sj = __shfl(src, j);
        float2 x0 = __half22float2(xsR[(size_t)sj * (H_DIM / 2) + lane]);
        a0 = fmaf(wj, x0.x, a0);
        a1 = fmaf(wj, x0.y, a1);
      }
    }
    float inv = 1.f / den;
    acc0 = fmaf(a0, inv, acc0);
    acc1 = fmaf(a1, inv, acc1);
  }
  acc0 = fmaxf(acc0, 0.f);
  acc1 = fmaxf(acc1, 0.f);
  float2 ov = {acc0, acc1};
  *(float2*)(Xout + ((size_t)t * N_NODES + node) * H_DIM + 2 * lane) = ov;
}

// ---------------------------------------------------------------------------
// out = X2[state] @ lin_w + lin_b : [N,128]@[128,64]; wave per node, lane=col
// ---------------------------------------------------------------------------
__global__ __launch_bounds__(256) void final_kernel(
    const float* __restrict__ X, const float* __restrict__ LW,
    const float* __restrict__ LB, float* __restrict__ out) {
  const int lane = threadIdx.x & 63;
  const int node = (blockIdx.x << 2) + (threadIdx.x >> 6);
  float xlo = X[(size_t)node * H_DIM + lane];
  float xhi = X[(size_t)node * H_DIM + 64 + lane];
  float acc = LB[lane];
  #pragma unroll
  for (int k = 0; k < 64; ++k) acc = fmaf(__shfl(xlo, k), LW[k * OUT_DIM + lane], acc);
  #pragma unroll
  for (int k = 0; k < 64; ++k) acc = fmaf(__shfl(xhi, k), LW[(64 + k) * OUT_DIM + lane], acc);
  out[(size_t)node * OUT_DIM + lane] = acc;
}

// ---------------------------------------------------------------------------
extern "C" void kernel_launch(void* const* d_in, const int* in_sizes, int n_in,
                              void* d_out, int out_size, void* d_ws, size_t ws_size,
                              hipStream_t stream) {
  (void)in_sizes; (void)n_in; (void)out_size; (void)ws_size;
  const float* x_state = (const float*)d_in[0];
  const float* x_action = (const float*)d_in[1];
  const float* x_bg = (const float*)d_in[2];
  const float* x_tt = (const float*)d_in[3];
  const int* EI = (const int*)d_in[4];
  const float* Wsrc0 = (const float*)d_in[5];
  const float* Wdst0 = (const float*)d_in[6];
  const float* asrc0 = (const float*)d_in[7];
  const float* adst0 = (const float*)d_in[8];
  const float* b0 = (const float*)d_in[9];
  const float* Wsrc1 = (const float*)d_in[10];
  const float* Wdst1 = (const float*)d_in[11];
  const float* asrc1 = (const float*)d_in[12];
  const float* adst1 = (const float*)d_in[13];
  const float* b1 = (const float*)d_in[14];
  const float* lin_w = (const float*)d_in[15];
  const float* lin_b = (const float*)d_in[16];
  float* out = (float*)d_out;

  char* p = (char*)d_ws;
  auto carve = [&](size_t bytes) -> void* {
    void* q = (void*)p;
    p += (bytes + 255) & ~(size_t)255;
    return q;
  };
  __half* XS = (__half*)carve(sizeof(__half) * (size_t)R_REL * N_NODES * H_DIM);
  float* Xa = (float*)carve(sizeof(float) * (size_t)4 * N_NODES * H_DIM);
  float* Xb = (float*)carve(sizeof(float) * (size_t)N_NODES * H_DIM);  // state only
  float* AS = (float*)carve(sizeof(float) * (size_t)R_REL * N_NODES);
  float* AD = (float*)carve(sizeof(float) * (size_t)R_REL * N_NODES);
  float* ASE = (float*)carve(sizeof(float) * (size_t)R_REL * E_EDGES);
  float* VS = (float*)carve(sizeof(float) * (size_t)R_REL * H_DIM);
  float* VD = (float*)carve(sizeof(float) * (size_t)R_REL * H_DIM);
  int* CNT = (int*)carve(sizeof(int) * (size_t)R_REL * N_NODES);
  int* OFF = (int*)carve(sizeof(int) * (size_t)R_REL * (N_NODES + 1));
  int* EL = (int*)carve(sizeof(int) * (size_t)R_REL * E_EDGES);

  // CSR build (shared by both layers)
  hipMemsetAsync(CNT, 0, sizeof(int) * (size_t)R_REL * N_NODES, stream);
  dim3 ge((E_EDGES + 255) / 256, R_REL);
  hist_kernel<<<ge, 256, 0, stream>>>(EI, CNT);
  scan_kernel<<<R_REL, 1024, 0, stream>>>(CNT, OFF);
  fill_kernel<<<ge, 256, 0, stream>>>(EI, CNT, EL);

  // ---- layer 0 (K = 64, all 12 relations) ----
  vcomp_kernel<IN_DIM><<<R_REL, IN_DIM, 0, stream>>>(Wsrc0, asrc0, Wdst0, adst0, VS, VD);
  gemm_xs_kernel<IN_DIM, false><<<dim3((N_NODES + 127) / 128, R_REL), 256, 0, stream>>>(
      x_state, x_action, x_bg, x_tt, Wsrc0, XS);
  attn_coef_kernel<IN_DIM, false><<<(R_REL * N_NODES) / 4, 256, 0, stream>>>(
      x_state, x_action, x_bg, x_tt, VS, VD, AS, AD);
  edge_as_kernel<false><<<dim3((E_EDGES + 255) / 256, R_REL), 256, 0, stream>>>(AS, EL, ASE);
  gather_kernel<<<dim3(N_NODES / 4, 4), 256, 0, stream>>>(
      (const __half2*)XS, ASE, AD, OFF, EL, b0, Xa);

  // ---- layer 1 (K = 128, only relations into 'state': r = 3,6,9) ----
  const float* a0p = Xa;
  const float* a1p = Xa + (size_t)N_NODES * H_DIM;
  const float* a2p = Xa + (size_t)2 * N_NODES * H_DIM;
  const float* a3p = Xa + (size_t)3 * N_NODES * H_DIM;
  vcomp_kernel<H_DIM><<<R_REL, H_DIM, 0, stream>>>(Wsrc1, asrc1, Wdst1, adst1, VS, VD);
  gemm_xs_kernel<H_DIM, true><<<dim3((N_NODES + 127) / 128, 3), 256, 0, stream>>>(
      a0p, a1p, a2p, a3p, Wsrc1, XS);
  attn_coef_kernel<H_DIM, true><<<(3 * N_NODES) / 4, 256, 0, stream>>>(
      a0p, a1p, a2p, a3p, VS, VD, AS, AD);
  edge_as_kernel<true><<<dim3((E_EDGES + 255) / 256, 3), 256, 0, stream>>>(AS, EL, ASE);
  gather_kernel<<<dim3(N_NODES / 4, 1), 256, 0, stream>>>(
      (const __half2*)XS, ASE, AD, OFF, EL, b1, Xb);

  // ---- final linear on 'state' ----
  final_kernel<<<N_NODES / 4, 256, 0, stream>>>(Xb, lin_w, lin_b, out);
}